// Round 10
// baseline (270.405 us; speedup 1.0000x reference)
//
#include <hip/hip_runtime.h>
#include <hip/hip_fp16.h>

// GCN 2-layer, pull-based CSR gather, fp16 dense intermediates.
// R10 = R9 + self-loop fix in gather1: acc seeds with h[node]*dv (final
// epilogue multiplies by dv once more -> dv^2, the correct self-loop norm).
// R9 bug: seeded dv^2 -> dv^3 after epilogue (absmax 8.8e-2).

typedef _Float16 half_t;
typedef _Float16 half2_t __attribute__((ext_vector_type(2)));
typedef _Float16 half4_t __attribute__((ext_vector_type(4)));

// ---------------- gemm1 body: 128x128 tile, BK=8 dbuf, 16 KB LDS ------------
// 256 threads; thread (tx,ty) computes rows r0+ty*8..+8, cols tx*4..+4 and
// 64+tx*4..+4. Unscaled fp16 epilogue.

__device__ __forceinline__ void gemm128x128(const float* __restrict__ A,
                                            const float* __restrict__ W,
                                            half_t* __restrict__ C, int M, int r0) {
    __shared__ float As[2][8][128];
    __shared__ float Bs[2][8][128];

    const int t = threadIdx.x;
    const int tx = t & 15;
    const int ty = t >> 4;

    const int ar = t >> 1;            // 0..127 row in tile
    const int ak = (t & 1) * 4;       // k offset 0 or 4
    const int arow = (r0 + ar < M) ? (r0 + ar) : (M - 1);
    const int br = t >> 5;            // 0..7
    const int bc = (t & 31) * 4;      // 0..124

    float4 aR, bR;
    aR = *(const float4*)&A[(size_t)arow * 128 + ak];
    bR = *(const float4*)&W[(size_t)br * 128 + bc];

    int buf = 0;
    As[buf][ak + 0][ar] = aR.x;
    As[buf][ak + 1][ar] = aR.y;
    As[buf][ak + 2][ar] = aR.z;
    As[buf][ak + 3][ar] = aR.w;
    *(float4*)&Bs[buf][br][bc] = bR;
    __syncthreads();

    float acc0[8][4], acc1[8][4];
#pragma unroll
    for (int r = 0; r < 8; ++r)
#pragma unroll
        for (int c = 0; c < 4; ++c) { acc0[r][c] = 0.f; acc1[r][c] = 0.f; }

#pragma unroll 1
    for (int it = 0; it < 16; ++it) {
        if (it + 1 < 16) {
            const int k0n = (it + 1) * 8;
            aR = *(const float4*)&A[(size_t)arow * 128 + k0n + ak];
            bR = *(const float4*)&W[(size_t)(k0n + br) * 128 + bc];
        }
#pragma unroll
        for (int k = 0; k < 8; ++k) {
            float4 a0 = *(const float4*)&As[buf][k][ty * 8];
            float4 a1 = *(const float4*)&As[buf][k][ty * 8 + 4];
            float4 b0 = *(const float4*)&Bs[buf][k][tx * 4];
            float4 b1 = *(const float4*)&Bs[buf][k][64 + tx * 4];
            float a_[8] = {a0.x, a0.y, a0.z, a0.w, a1.x, a1.y, a1.z, a1.w};
            float b0_[4] = {b0.x, b0.y, b0.z, b0.w};
            float b1_[4] = {b1.x, b1.y, b1.z, b1.w};
#pragma unroll
            for (int r = 0; r < 8; ++r)
#pragma unroll
                for (int c = 0; c < 4; ++c) {
                    acc0[r][c] = fmaf(a_[r], b0_[c], acc0[r][c]);
                    acc1[r][c] = fmaf(a_[r], b1_[c], acc1[r][c]);
                }
        }
        if (it + 1 < 16) {
            int nb = buf ^ 1;
            As[nb][ak + 0][ar] = aR.x;
            As[nb][ak + 1][ar] = aR.y;
            As[nb][ak + 2][ar] = aR.z;
            As[nb][ak + 3][ar] = aR.w;
            *(float4*)&Bs[nb][br][bc] = bR;
            __syncthreads();
            buf = nb;
        }
    }

#pragma unroll
    for (int r = 0; r < 8; ++r) {
        int row = r0 + ty * 8 + r;
        if (row < M) {
            half4_t p;
            p.x = (half_t)acc0[r][0]; p.y = (half_t)acc0[r][1];
            p.z = (half_t)acc0[r][2]; p.w = (half_t)acc0[r][3];
            *(half4_t*)&C[(size_t)row * 128 + tx * 4] = p;
            half4_t q;
            q.x = (half_t)acc1[r][0]; q.y = (half_t)acc1[r][1];
            q.z = (half_t)acc1[r][2]; q.w = (half_t)acc1[r][3];
            *(half4_t*)&C[(size_t)row * 128 + 64 + tx * 4] = q;
        }
    }
}

// ---------------- k1: gemm1 blocks first, then 4-way degree blocks ----------

__launch_bounds__(256)
__global__ void gemm_deg_k(const float* __restrict__ A, const float* __restrict__ W,
                           half_t* __restrict__ C, int M, int Gg1,
                           const int* __restrict__ edst, int* __restrict__ deg4,
                           int E, int N) {
    int b = blockIdx.x;
    if (b < Gg1) {
        gemm128x128(A, W, C, M, b * 128);
    } else {
        int i = (b - Gg1) * 256 + threadIdx.x;
        int E4 = E >> 2;
        if (i < E4) {
            int4 d = ((const int4*)edst)[i];
            int* cnt = deg4 + (size_t)(i & 3) * N;   // class (e>>2)&3 == i&3
            atomicAdd(&cnt[d.x], 1);
            atomicAdd(&cnt[d.y], 1);
            atomicAdd(&cnt[d.z], 1);
            atomicAdd(&cnt[d.w], 1);
        }
        int r = (E4 << 2) + i;
        if (r < E) atomicAdd(&deg4[(size_t)((r >> 2) & 3) * N + edst[r]], 1);
    }
}

// ---------------- k2: sum 4 copies, dinv, partial excl scan, cursor bases ---

__global__ void scan1_k(const int* __restrict__ deg4, int* __restrict__ rs,
                        int* __restrict__ cur4, int* __restrict__ bsums,
                        float* __restrict__ dinv, int n) {
    __shared__ int lds[256];
    int t = threadIdx.x;
    int base = blockIdx.x * 1024 + t * 4;
    int d[4][4];
    int tot[4] = {0, 0, 0, 0};
#pragma unroll
    for (int j = 0; j < 4; ++j) {
        int node = base + j;
        if (node < n) {
            d[j][0] = deg4[node];
            d[j][1] = deg4[(size_t)n + node];
            d[j][2] = deg4[(size_t)2 * n + node];
            d[j][3] = deg4[(size_t)3 * n + node];
            tot[j] = d[j][0] + d[j][1] + d[j][2] + d[j][3];
            dinv[node] = rsqrtf(1.0f + (float)tot[j]);
        }
    }
    lds[t] = tot[0] + tot[1] + tot[2] + tot[3];
    __syncthreads();
    for (int off = 1; off < 256; off <<= 1) {
        int x = (t >= off) ? lds[t - off] : 0;
        __syncthreads();
        lds[t] += x;
        __syncthreads();
    }
    int run = (t > 0) ? lds[t - 1] : 0;
    if (t == 255) bsums[blockIdx.x] = lds[255];
#pragma unroll
    for (int j = 0; j < 4; ++j) {
        int node = base + j;
        if (node < n) {
            rs[node] = run;                                   // partial (per-1024-block)
            cur4[node] = run;
            cur4[(size_t)n + node] = run + d[j][0];
            cur4[(size_t)2 * n + node] = run + d[j][0] + d[j][1];
            cur4[(size_t)3 * n + node] = run + d[j][0] + d[j][1] + d[j][2];
            run += tot[j];
        }
    }
}

// helper: inclusive 64-scan of bsums into pre[] (every consumer block redoes it)
__device__ __forceinline__ void scan_bsums(const int* __restrict__ bsums, int nb,
                                           int* pre) {
    int t = threadIdx.x;
    if (t < 64) {
        int v = (t < nb) ? bsums[t] : 0;
#pragma unroll
        for (int off = 1; off < 64; off <<= 1) {
            int u = __shfl_up(v, off);
            if (t >= off) v += u;
        }
        pre[t] = v;
    }
}

// ---------------- k3: CSR fill via 4-way cursors + inline scan fixup --------

template <typename IDX>
__global__ void fill_k(const int* __restrict__ esrc, const int* __restrict__ edst,
                       int* __restrict__ cur4, IDX* __restrict__ ssrc,
                       const int* __restrict__ bsums, int nb, int E, int N) {
    __shared__ int pre[64];
    scan_bsums(bsums, nb, pre);
    __syncthreads();
    int i = blockIdx.x * 512 + threadIdx.x;
    if (i < E) {
        int d = edst[i];
        int p = atomicAdd(&cur4[(size_t)((i >> 2) & 3) * N + d], 1);
        p += (d >> 10) ? pre[(d >> 10) - 1] : 0;
        ssrc[p] = (IDX)esrc[i];
    }
    int j = i + 256;
    if (j < E) {
        int d = edst[j];
        int p = atomicAdd(&cur4[(size_t)((j >> 2) & 3) * N + d], 1);
        p += (d >> 10) ? pre[(d >> 10) - 1] : 0;
        ssrc[p] = (IDX)esrc[j];
    }
}

// ---------------- gather1: 128-dim, fold dinv[src] per edge, fp16 out+relu --
// out = relu( dv * ( h[node]*dv + sum_s h[s]*dinv[s] ) + b )

template <typename IDX>
__global__ void gather1_k(const half_t* __restrict__ hs, const IDX* __restrict__ ssrc,
                          const int* __restrict__ rs, const int* __restrict__ bsums,
                          int nb, const float* __restrict__ dinv,
                          const float* __restrict__ bias,
                          half_t* __restrict__ o, int N, int E) {
    __shared__ int pre[64];
    scan_bsums(bsums, nb, pre);
    __syncthreads();
    int node = (int)((blockIdx.x * blockDim.x + threadIdx.x) >> 6);
    int lane = threadIdx.x & 63;
    if (node >= N) return;

    int start = rs[node] + ((node >> 10) ? pre[(node >> 10) - 1] : 0);
    int end;
    if (node + 1 < N) {
        int nn = node + 1;
        end = rs[nn] + ((nn >> 10) ? pre[(nn >> 10) - 1] : 0);
    } else {
        end = E;
    }
    float dv = dinv[node];

    const half_t* hp = hs + 2 * lane;
    half2_t sv = *(const half2_t*)&hp[(size_t)node * 128];   // self loop
    float2 acc;
    acc.x = (float)sv.x * dv;        // FIXED: *dv (epilogue adds the 2nd dv)
    acc.y = (float)sv.y * dv;
    for (int base = start; base < end; base += 64) {
        int n = end - base;
        if (n > 64) n = 64;
        int gi = (base + lane < end) ? (base + lane) : base;
        int idx = (int)ssrc[gi];
        float dw = dinv[idx];
        int e = 0;
        for (; e + 4 <= n; e += 4) {
            int s0 = __shfl(idx, e + 0);
            int s1 = __shfl(idx, e + 1);
            int s2 = __shfl(idx, e + 2);
            int s3 = __shfl(idx, e + 3);
            float w0 = __shfl(dw, e + 0);
            float w1 = __shfl(dw, e + 1);
            float w2 = __shfl(dw, e + 2);
            float w3 = __shfl(dw, e + 3);
            half2_t a0 = *(const half2_t*)&hp[(size_t)s0 * 128];
            half2_t a1 = *(const half2_t*)&hp[(size_t)s1 * 128];
            half2_t a2 = *(const half2_t*)&hp[(size_t)s2 * 128];
            half2_t a3 = *(const half2_t*)&hp[(size_t)s3 * 128];
            acc.x = fmaf((float)a0.x, w0, acc.x);
            acc.y = fmaf((float)a0.y, w0, acc.y);
            acc.x = fmaf((float)a1.x, w1, acc.x);
            acc.y = fmaf((float)a1.y, w1, acc.y);
            acc.x = fmaf((float)a2.x, w2, acc.x);
            acc.y = fmaf((float)a2.y, w2, acc.y);
            acc.x = fmaf((float)a3.x, w3, acc.x);
            acc.y = fmaf((float)a3.y, w3, acc.y);
        }
        for (; e < n; ++e) {
            int s0 = __shfl(idx, e);
            float w0 = __shfl(dw, e);
            half2_t a0 = *(const half2_t*)&hp[(size_t)s0 * 128];
            acc.x = fmaf((float)a0.x, w0, acc.x);
            acc.y = fmaf((float)a0.y, w0, acc.y);
        }
    }
    float2 bb = *(const float2*)&bias[2 * lane];
    acc.x = fmaxf(acc.x * dv + bb.x, 0.f);
    acc.y = fmaxf(acc.y * dv + bb.y, 0.f);
    half2_t st;
    st.x = (half_t)acc.x;
    st.y = (half_t)acc.y;
    *(half2_t*)&o[(size_t)node * 128 + 2 * lane] = st;
}

// ---------------- gemm2: [M,128]fp16 @ [128,64] -> fp16, *dinv[row] ---------

__launch_bounds__(256)
__global__ void gemm2_k(const half_t* __restrict__ A, const float* __restrict__ W,
                        const float* __restrict__ dinv, half_t* __restrict__ C, int M) {
    constexpr int BN = 64, BK = 16, KI = 128 / BK;
    __shared__ float As[2][BK][64 + 4];
    __shared__ float Bs[2][BK][BN];

    const int t = threadIdx.x;
    const int tx = t & 15;
    const int ty = t >> 4;
    const int r0 = blockIdx.x * 64;

    const int ar = t >> 2;
    const int ak = (t & 3) * 4;
    const int arow = (r0 + ar < M) ? (r0 + ar) : (M - 1);
    const int br0 = t >> 4;
    const int bc0 = (t & 15) * 4;

    half4_t aR;
    float4 bR0;
    aR = *(const half4_t*)&A[(size_t)arow * 128 + ak];
    bR0 = *(const float4*)&W[(size_t)br0 * BN + bc0];

    int buf = 0;
    As[buf][ak + 0][ar] = (float)aR.x;
    As[buf][ak + 1][ar] = (float)aR.y;
    As[buf][ak + 2][ar] = (float)aR.z;
    As[buf][ak + 3][ar] = (float)aR.w;
    *(float4*)&Bs[buf][br0][bc0] = bR0;
    __syncthreads();

    float acc0[4][4];
#pragma unroll
    for (int r = 0; r < 4; ++r)
#pragma unroll
        for (int c = 0; c < 4; ++c) acc0[r][c] = 0.f;

#pragma unroll 1
    for (int it = 0; it < KI; ++it) {
        const int k0n = (it + 1) * BK;
        if (it + 1 < KI) {
            aR = *(const half4_t*)&A[(size_t)arow * 128 + k0n + ak];
            bR0 = *(const float4*)&W[(size_t)(k0n + br0) * BN + bc0];
        }
#pragma unroll
        for (int k = 0; k < BK; ++k) {
            float4 av = *(const float4*)&As[buf][k][ty * 4];
            float4 b0 = *(const float4*)&Bs[buf][k][tx * 4];
            float a_[4] = {av.x, av.y, av.z, av.w};
            float b0_[4] = {b0.x, b0.y, b0.z, b0.w};
#pragma unroll
            for (int r = 0; r < 4; ++r)
#pragma unroll
                for (int c = 0; c < 4; ++c)
                    acc0[r][c] = fmaf(a_[r], b0_[c], acc0[r][c]);
        }
        if (it + 1 < KI) {
            int nb = buf ^ 1;
            As[nb][ak + 0][ar] = (float)aR.x;
            As[nb][ak + 1][ar] = (float)aR.y;
            As[nb][ak + 2][ar] = (float)aR.z;
            As[nb][ak + 3][ar] = (float)aR.w;
            *(float4*)&Bs[nb][br0][bc0] = bR0;
            __syncthreads();
            buf = nb;
        }
    }

#pragma unroll
    for (int r = 0; r < 4; ++r) {
        int row = r0 + ty * 4 + r;
        if (row < M) {
            float s = dinv[row];
            half4_t p;
            p.x = (half_t)(acc0[r][0] * s); p.y = (half_t)(acc0[r][1] * s);
            p.z = (half_t)(acc0[r][2] * s); p.w = (half_t)(acc0[r][3] * s);
            *(half4_t*)&C[(size_t)row * BN + tx * 4] = p;
        }
    }
}

// ---------------- gather2: 64-dim, hs pre-scaled, fp32 out ------------------

template <typename IDX>
__global__ void gather2_k(const half_t* __restrict__ hs, const IDX* __restrict__ ssrc,
                          const int* __restrict__ rs, const int* __restrict__ bsums,
                          int nb, const float* __restrict__ dinv,
                          const float* __restrict__ bias,
                          float* __restrict__ o, int N, int E) {
    __shared__ int pre[64];
    scan_bsums(bsums, nb, pre);
    __syncthreads();
    int node = (int)((blockIdx.x * blockDim.x + threadIdx.x) >> 6);
    int lane = threadIdx.x & 63;
    if (node >= N) return;

    int start = rs[node] + ((node >> 10) ? pre[(node >> 10) - 1] : 0);
    int end;
    if (node + 1 < N) {
        int nn = node + 1;
        end = rs[nn] + ((nn >> 10) ? pre[(nn >> 10) - 1] : 0);
    } else {
        end = E;
    }
    float dv = dinv[node];

    const half_t* hp = hs + lane;
    float acc = (float)hp[(size_t)node * 64];
    for (int base = start; base < end; base += 64) {
        int n = end - base;
        if (n > 64) n = 64;
        int gi = (base + lane < end) ? (base + lane) : base;
        int idx = (int)ssrc[gi];
        int e = 0;
        for (; e + 4 <= n; e += 4) {
            int s0 = __shfl(idx, e + 0);
            int s1 = __shfl(idx, e + 1);
            int s2 = __shfl(idx, e + 2);
            int s3 = __shfl(idx, e + 3);
            float a0 = (float)hp[(size_t)s0 * 64];
            float a1 = (float)hp[(size_t)s1 * 64];
            float a2 = (float)hp[(size_t)s2 * 64];
            float a3 = (float)hp[(size_t)s3 * 64];
            acc += (a0 + a1) + (a2 + a3);
        }
        for (; e < n; ++e) {
            int s0 = __shfl(idx, e);
            acc += (float)hp[(size_t)s0 * 64];
        }
    }
    acc = acc * dv + bias[lane];
    o[(size_t)node * 64 + lane] = acc;
}

// ---------------- launcher ----------------

extern "C" void kernel_launch(void* const* d_in, const int* in_sizes, int n_in,
                              void* d_out, int out_size, void* d_ws, size_t ws_size,
                              hipStream_t stream) {
    const float* x  = (const float*)d_in[0];
    const int*   ei = (const int*)d_in[1];
    const float* W1 = (const float*)d_in[2];
    const float* b1 = (const float*)d_in[3];
    const float* W2 = (const float*)d_in[4];
    const float* b2 = (const float*)d_in[5];
    float* out = (float*)d_out;

    const int N = in_sizes[0] / 128;
    const int E = in_sizes[1] / 2;
    const int* esrc = ei;
    const int* edst = ei + E;

    // workspace layout
    int* deg4  = (int*)d_ws;                          // 4N
    int* cur4  = deg4 + (size_t)4 * N;                // 4N
    int* rs    = cur4 + (size_t)4 * N;                // N
    int* bsums = rs + N;                              // 64
    unsigned short* ssrc16 = (unsigned short*)(bsums + 64);  // E (uint16)
    int* ssrc32 = (int*)(bsums + 64);                 // E (int32 fallback)
    float* dinv = (float*)((char*)(bsums + 64) + (size_t)E * 4); // N
    half_t* hs1 = (half_t*)(dinv + N);                // N*128 fp16 (reused as hs2)
    half_t* g1  = hs1 + (size_t)N * 128;              // N*128 fp16
    half_t* hs2 = hs1;

    const int nb = (N + 1023) / 1024;
    const int Gg1  = (N + 127) / 128;
    const int Gdeg = ((E >> 2) + 255) / 256;
    const int Gfill = (E + 511) / 512;

    hipMemsetAsync(deg4, 0, (size_t)4 * N * 4, stream);

    // k1: gemm1 (128x128 tiles, unscaled fp16) + 4-way degree atomics
    hipLaunchKernelGGL(gemm_deg_k, dim3(Gg1 + Gdeg), dim3(256), 0, stream,
                       x, W1, hs1, N, Gg1, edst, deg4, E, N);
    // k2: sum copies + dinv + partial exclusive scan + per-class cursor bases
    hipLaunchKernelGGL(scan1_k, dim3(nb), dim3(256), 0, stream,
                       deg4, rs, cur4, bsums, dinv, N);

    if (N <= 65536) {
        hipLaunchKernelGGL((fill_k<unsigned short>), dim3(Gfill), dim3(256), 0, stream,
                           esrc, edst, cur4, ssrc16, bsums, nb, E, N);
        hipLaunchKernelGGL((gather1_k<unsigned short>),
                           dim3((N + 3) / 4), dim3(256), 0, stream,
                           hs1, ssrc16, rs, bsums, nb, dinv, b1, g1, N, E);
        hipLaunchKernelGGL(gemm2_k, dim3((N + 63) / 64), dim3(256), 0, stream,
                           g1, W2, dinv, hs2, N);
        hipLaunchKernelGGL((gather2_k<unsigned short>),
                           dim3((N + 3) / 4), dim3(256), 0, stream,
                           hs2, ssrc16, rs, bsums, nb, dinv, b2, out, N, E);
    } else {
        hipLaunchKernelGGL((fill_k<int>), dim3(Gfill), dim3(256), 0, stream,
                           esrc, edst, cur4, ssrc32, bsums, nb, E, N);
        hipLaunchKernelGGL((gather1_k<int>),
                           dim3((N + 3) / 4), dim3(256), 0, stream,
                           hs1, ssrc32, rs, bsums, nb, dinv, b1, g1, N, E);
        hipLaunchKernelGGL(gemm2_k, dim3((N + 63) / 64), dim3(256), 0, stream,
                           g1, W2, dinv, hs2, N);
        hipLaunchKernelGGL((gather2_k<int>),
                           dim3((N + 3) / 4), dim3(256), 0, stream,
                           hs2, ssrc32, rs, bsums, nb, dinv, b2, out, N, E);
    }
}

// Round 12
// 197.854 us; speedup vs baseline: 1.3667x; 1.3667x over previous
//
#include <hip/hip_runtime.h>
#include <hip/hip_fp16.h>

// GCN 2-layer, pull-based CSR gather, fp16 dense intermediates.
// R12 = R11 with the pass-A addressing fix: each bucket owns a FIXED-CAPACITY
// segment ebuf[b*CAP .. b*CAP+CAP) (CAP=8192 >> expected 4096±64), so the
// per-bucket cursor atomicAdd yields a valid absolute slot. R11 treated the
// per-bucket cursor as an absolute ebuf offset -> all buckets overwrote the
// same region (absmax 80).
// Assumes N <= 65536 (src fits 16 bits of packed word; <=256 buckets).

typedef _Float16 half_t;
typedef _Float16 half2_t __attribute__((ext_vector_type(2)));
typedef _Float16 half4_t __attribute__((ext_vector_type(4)));

#define BKT_CAP 8192   // per-bucket ebuf capacity (expected load 4096, sigma 64)

// inclusive block scan over 256 threads (4 waves); caller provides 4-int LDS
__device__ __forceinline__ int incl_scan256(int v, volatile int* wsum) {
    int t = threadIdx.x, lane = t & 63, w = t >> 6;
#pragma unroll
    for (int off = 1; off < 64; off <<= 1) {
        int u = __shfl_up(v, off);
        if (lane >= off) v += u;
    }
    if (lane == 63) wsum[w] = v;
    __syncthreads();
    int add = 0;
#pragma unroll
    for (int i = 0; i < 3; ++i)
        if (i < w) add += wsum[i];
    return v + add;
}

// ---------------- gemm1 body: 128x128 tile, BK=8 dbuf, 16 KB LDS ------------

__device__ __forceinline__ void gemm128x128(const float* __restrict__ A,
                                            const float* __restrict__ W,
                                            half_t* __restrict__ C, int M, int r0) {
    __shared__ float As[2][8][128];
    __shared__ float Bs[2][8][128];

    const int t = threadIdx.x;
    const int tx = t & 15;
    const int ty = t >> 4;

    const int ar = t >> 1;
    const int ak = (t & 1) * 4;
    const int arow = (r0 + ar < M) ? (r0 + ar) : (M - 1);
    const int br = t >> 5;
    const int bc = (t & 31) * 4;

    float4 aR, bR;
    aR = *(const float4*)&A[(size_t)arow * 128 + ak];
    bR = *(const float4*)&W[(size_t)br * 128 + bc];

    int buf = 0;
    As[buf][ak + 0][ar] = aR.x;
    As[buf][ak + 1][ar] = aR.y;
    As[buf][ak + 2][ar] = aR.z;
    As[buf][ak + 3][ar] = aR.w;
    *(float4*)&Bs[buf][br][bc] = bR;
    __syncthreads();

    float acc0[8][4], acc1[8][4];
#pragma unroll
    for (int r = 0; r < 8; ++r)
#pragma unroll
        for (int c = 0; c < 4; ++c) { acc0[r][c] = 0.f; acc1[r][c] = 0.f; }

#pragma unroll 1
    for (int it = 0; it < 16; ++it) {
        if (it + 1 < 16) {
            const int k0n = (it + 1) * 8;
            aR = *(const float4*)&A[(size_t)arow * 128 + k0n + ak];
            bR = *(const float4*)&W[(size_t)(k0n + br) * 128 + bc];
        }
#pragma unroll
        for (int k = 0; k < 8; ++k) {
            float4 a0 = *(const float4*)&As[buf][k][ty * 8];
            float4 a1 = *(const float4*)&As[buf][k][ty * 8 + 4];
            float4 b0 = *(const float4*)&Bs[buf][k][tx * 4];
            float4 b1 = *(const float4*)&Bs[buf][k][64 + tx * 4];
            float a_[8] = {a0.x, a0.y, a0.z, a0.w, a1.x, a1.y, a1.z, a1.w};
            float b0_[4] = {b0.x, b0.y, b0.z, b0.w};
            float b1_[4] = {b1.x, b1.y, b1.z, b1.w};
#pragma unroll
            for (int r = 0; r < 8; ++r)
#pragma unroll
                for (int c = 0; c < 4; ++c) {
                    acc0[r][c] = fmaf(a_[r], b0_[c], acc0[r][c]);
                    acc1[r][c] = fmaf(a_[r], b1_[c], acc1[r][c]);
                }
        }
        if (it + 1 < 16) {
            int nb = buf ^ 1;
            As[nb][ak + 0][ar] = aR.x;
            As[nb][ak + 1][ar] = aR.y;
            As[nb][ak + 2][ar] = aR.z;
            As[nb][ak + 3][ar] = aR.w;
            *(float4*)&Bs[nb][br][bc] = bR;
            __syncthreads();
            buf = nb;
        }
    }

#pragma unroll
    for (int r = 0; r < 8; ++r) {
        int row = r0 + ty * 8 + r;
        if (row < M) {
            half4_t p;
            p.x = (half_t)acc0[r][0]; p.y = (half_t)acc0[r][1];
            p.z = (half_t)acc0[r][2]; p.w = (half_t)acc0[r][3];
            *(half4_t*)&C[(size_t)row * 128 + tx * 4] = p;
            half4_t q;
            q.x = (half_t)acc1[r][0]; q.y = (half_t)acc1[r][1];
            q.z = (half_t)acc1[r][2]; q.w = (half_t)acc1[r][3];
            *(half4_t*)&C[(size_t)row * 128 + 64 + tx * 4] = q;
        }
    }
}

// ---------------- k1: gemm1 blocks, then pass-A binning blocks --------------
// Pass A: 4096 edges/block staged in regs; LDS histogram over buckets
// (dst>>8); block scan; one global atomicAdd per bucket reserves a range in
// the bucket's FIXED segment [bkt*BKT_CAP ...); packed (src<<8 | dst&255)
// written segment-contiguous.

__launch_bounds__(256)
__global__ void gemm_binA_k(const float* __restrict__ A, const float* __restrict__ W,
                            half_t* __restrict__ C, int M, int Gg1,
                            const int* __restrict__ esrc, const int* __restrict__ edst,
                            int* __restrict__ bucket_cnt, unsigned int* __restrict__ ebuf,
                            int E) {
    int b = blockIdx.x;
    if (b < Gg1) {
        gemm128x128(A, W, C, M, b * 128);
        return;
    }
    __shared__ int cntA[256];
    __shared__ int curA[256];
    __shared__ int deltaA[256];
    __shared__ int wsumA[4];

    const int t = threadIdx.x;
    const int base = (b - Gg1) * 4096;
    int ls[16], ld[16];

    cntA[t] = 0;
    __syncthreads();
#pragma unroll
    for (int j = 0; j < 16; ++j) {
        int idx = base + j * 256 + t;
        if (idx < E) {
            ls[j] = esrc[idx];
            ld[j] = edst[idx];
            atomicAdd(&cntA[ld[j] >> 8], 1);
        } else {
            ls[j] = -1;
            ld[j] = 0;
        }
    }
    __syncthreads();

    int c = cntA[t];
    int incl = incl_scan256(c, wsumA);      // contains a __syncthreads
    int excl = incl - c;
    int gbase = atomicAdd(&bucket_cnt[t], c);       // offset within bucket segment
    deltaA[t] = t * BKT_CAP + gbase - excl;         // FIX: absolute = seg base + off
    curA[t] = excl;
    __syncthreads();

#pragma unroll
    for (int j = 0; j < 16; ++j) {
        if (ls[j] >= 0) {
            int bkt = ld[j] >> 8;
            int p = atomicAdd(&curA[bkt], 1);
            ebuf[deltaA[bkt] + p] = ((unsigned int)ls[j] << 8) | ((unsigned int)ld[j] & 255u);
        }
    }
}

// ---------------- k2 (pass B): per-bucket counting sort, emits rs/dinv/ssrc -
// One 256-thread block per bucket of 256 nodes. Reads the bucket's segment
// (ebuf[b*BKT_CAP ...]), compacts sorted src16 into ssrc[gb ...] where gb is
// the scan of actual bucket counts. Scatter stores span ~8 KB -> L1-resident.

__launch_bounds__(256)
__global__ void binB_k(const int* __restrict__ bucket_cnt,
                       const unsigned int* __restrict__ ebuf,
                       unsigned short* __restrict__ ssrc,
                       int* __restrict__ rs, float* __restrict__ dinv,
                       int N, int NB) {
    __shared__ int cnt[256];
    __shared__ int pre[256];
    __shared__ int wsum1[4];
    __shared__ int wsum2[4];

    const int t = threadIdx.x;
    const int b = blockIdx.x;

    // redundant per-block scan of actual bucket sizes -> my output base
    int v = (t < NB) ? bucket_cnt[t] : 0;
    int inclb = incl_scan256(v, wsum1);
    pre[t] = inclb;
    __syncthreads();
    const int gb = (b > 0) ? pre[b - 1] : 0;    // output base in ssrc
    const int sz = pre[b] - gb;                 // this bucket's edge count
    const unsigned int* seg = ebuf + (size_t)b * BKT_CAP;

    cnt[t] = 0;
    __syncthreads();
    for (int i = t; i < sz; i += 256) {
        unsigned int pk = seg[i];
        atomicAdd(&cnt[pk & 255u], 1);
    }
    __syncthreads();

    int c = cnt[t];
    int incl = incl_scan256(c, wsum2);
    int excl = incl - c;
    int node = b * 256 + t;
    if (node < N) {
        rs[node] = gb + excl;
        dinv[node] = rsqrtf(1.0f + (float)c);
    }
    __syncthreads();            // everyone done reading cnt
    cnt[t] = excl;              // reuse as local cursor
    __syncthreads();

    for (int i = t; i < sz; i += 256) {
        unsigned int pk = seg[i];
        int p = atomicAdd(&cnt[pk & 255u], 1);
        ssrc[gb + p] = (unsigned short)(pk >> 8);
    }
}

// ---------------- gather1: 128-dim, fold dinv[src] per edge, fp16 out+relu --
// out = relu( dv * ( h[node]*dv + sum_s h[s]*dinv[s] ) + b )

__global__ void gather1_k(const half_t* __restrict__ hs,
                          const unsigned short* __restrict__ ssrc,
                          const int* __restrict__ rs,
                          const float* __restrict__ dinv,
                          const float* __restrict__ bias,
                          half_t* __restrict__ o, int N, int E) {
    int node = (int)((blockIdx.x * blockDim.x + threadIdx.x) >> 6);
    int lane = threadIdx.x & 63;
    if (node >= N) return;

    int start = rs[node];
    int end = (node + 1 < N) ? rs[node + 1] : E;
    float dv = dinv[node];

    const half_t* hp = hs + 2 * lane;
    half2_t sv = *(const half2_t*)&hp[(size_t)node * 128];   // self loop
    float2 acc;
    acc.x = (float)sv.x * dv;        // epilogue multiplies by dv again -> dv^2
    acc.y = (float)sv.y * dv;
    for (int base = start; base < end; base += 64) {
        int n = end - base;
        if (n > 64) n = 64;
        int gi = (base + lane < end) ? (base + lane) : base;
        int idx = (int)ssrc[gi];
        float dw = dinv[idx];
        int e = 0;
        for (; e + 4 <= n; e += 4) {
            int s0 = __shfl(idx, e + 0);
            int s1 = __shfl(idx, e + 1);
            int s2 = __shfl(idx, e + 2);
            int s3 = __shfl(idx, e + 3);
            float w0 = __shfl(dw, e + 0);
            float w1 = __shfl(dw, e + 1);
            float w2 = __shfl(dw, e + 2);
            float w3 = __shfl(dw, e + 3);
            half2_t a0 = *(const half2_t*)&hp[(size_t)s0 * 128];
            half2_t a1 = *(const half2_t*)&hp[(size_t)s1 * 128];
            half2_t a2 = *(const half2_t*)&hp[(size_t)s2 * 128];
            half2_t a3 = *(const half2_t*)&hp[(size_t)s3 * 128];
            acc.x = fmaf((float)a0.x, w0, acc.x);
            acc.y = fmaf((float)a0.y, w0, acc.y);
            acc.x = fmaf((float)a1.x, w1, acc.x);
            acc.y = fmaf((float)a1.y, w1, acc.y);
            acc.x = fmaf((float)a2.x, w2, acc.x);
            acc.y = fmaf((float)a2.y, w2, acc.y);
            acc.x = fmaf((float)a3.x, w3, acc.x);
            acc.y = fmaf((float)a3.y, w3, acc.y);
        }
        for (; e < n; ++e) {
            int s0 = __shfl(idx, e);
            float w0 = __shfl(dw, e);
            half2_t a0 = *(const half2_t*)&hp[(size_t)s0 * 128];
            acc.x = fmaf((float)a0.x, w0, acc.x);
            acc.y = fmaf((float)a0.y, w0, acc.y);
        }
    }
    float2 bb = *(const float2*)&bias[2 * lane];
    acc.x = fmaxf(acc.x * dv + bb.x, 0.f);
    acc.y = fmaxf(acc.y * dv + bb.y, 0.f);
    half2_t st;
    st.x = (half_t)acc.x;
    st.y = (half_t)acc.y;
    *(half2_t*)&o[(size_t)node * 128 + 2 * lane] = st;
}

// ---------------- gemm2: [M,128]fp16 @ [128,64] -> fp16, *dinv[row] ---------

__launch_bounds__(256)
__global__ void gemm2_k(const half_t* __restrict__ A, const float* __restrict__ W,
                        const float* __restrict__ dinv, half_t* __restrict__ C, int M) {
    constexpr int BN = 64, BK = 16, KI = 128 / BK;
    __shared__ float As[2][BK][64 + 4];
    __shared__ float Bs[2][BK][BN];

    const int t = threadIdx.x;
    const int tx = t & 15;
    const int ty = t >> 4;
    const int r0 = blockIdx.x * 64;

    const int ar = t >> 2;
    const int ak = (t & 3) * 4;
    const int arow = (r0 + ar < M) ? (r0 + ar) : (M - 1);
    const int br0 = t >> 4;
    const int bc0 = (t & 15) * 4;

    half4_t aR;
    float4 bR0;
    aR = *(const half4_t*)&A[(size_t)arow * 128 + ak];
    bR0 = *(const float4*)&W[(size_t)br0 * BN + bc0];

    int buf = 0;
    As[buf][ak + 0][ar] = (float)aR.x;
    As[buf][ak + 1][ar] = (float)aR.y;
    As[buf][ak + 2][ar] = (float)aR.z;
    As[buf][ak + 3][ar] = (float)aR.w;
    *(float4*)&Bs[buf][br0][bc0] = bR0;
    __syncthreads();

    float acc0[4][4];
#pragma unroll
    for (int r = 0; r < 4; ++r)
#pragma unroll
        for (int c = 0; c < 4; ++c) acc0[r][c] = 0.f;

#pragma unroll 1
    for (int it = 0; it < KI; ++it) {
        const int k0n = (it + 1) * BK;
        if (it + 1 < KI) {
            aR = *(const half4_t*)&A[(size_t)arow * 128 + k0n + ak];
            bR0 = *(const float4*)&W[(size_t)(k0n + br0) * BN + bc0];
        }
#pragma unroll
        for (int k = 0; k < BK; ++k) {
            float4 av = *(const float4*)&As[buf][k][ty * 4];
            float4 b0 = *(const float4*)&Bs[buf][k][tx * 4];
            float a_[4] = {av.x, av.y, av.z, av.w};
            float b0_[4] = {b0.x, b0.y, b0.z, b0.w};
#pragma unroll
            for (int r = 0; r < 4; ++r)
#pragma unroll
                for (int c = 0; c < 4; ++c)
                    acc0[r][c] = fmaf(a_[r], b0_[c], acc0[r][c]);
        }
        if (it + 1 < KI) {
            int nb = buf ^ 1;
            As[nb][ak + 0][ar] = (float)aR.x;
            As[nb][ak + 1][ar] = (float)aR.y;
            As[nb][ak + 2][ar] = (float)aR.z;
            As[nb][ak + 3][ar] = (float)aR.w;
            *(float4*)&Bs[nb][br0][bc0] = bR0;
            __syncthreads();
            buf = nb;
        }
    }

#pragma unroll
    for (int r = 0; r < 4; ++r) {
        int row = r0 + ty * 4 + r;
        if (row < M) {
            float s = dinv[row];
            half4_t p;
            p.x = (half_t)(acc0[r][0] * s); p.y = (half_t)(acc0[r][1] * s);
            p.z = (half_t)(acc0[r][2] * s); p.w = (half_t)(acc0[r][3] * s);
            *(half4_t*)&C[(size_t)row * BN + tx * 4] = p;
        }
    }
}

// ---------------- gather2: 64-dim, hs pre-scaled, fp32 out ------------------

__global__ void gather2_k(const half_t* __restrict__ hs,
                          const unsigned short* __restrict__ ssrc,
                          const int* __restrict__ rs,
                          const float* __restrict__ dinv,
                          const float* __restrict__ bias,
                          float* __restrict__ o, int N, int E) {
    int node = (int)((blockIdx.x * blockDim.x + threadIdx.x) >> 6);
    int lane = threadIdx.x & 63;
    if (node >= N) return;

    int start = rs[node];
    int end = (node + 1 < N) ? rs[node + 1] : E;
    float dv = dinv[node];

    const half_t* hp = hs + lane;
    float acc = (float)hp[(size_t)node * 64];
    for (int base = start; base < end; base += 64) {
        int n = end - base;
        if (n > 64) n = 64;
        int gi = (base + lane < end) ? (base + lane) : base;
        int idx = (int)ssrc[gi];
        int e = 0;
        for (; e + 4 <= n; e += 4) {
            int s0 = __shfl(idx, e + 0);
            int s1 = __shfl(idx, e + 1);
            int s2 = __shfl(idx, e + 2);
            int s3 = __shfl(idx, e + 3);
            float a0 = (float)hp[(size_t)s0 * 64];
            float a1 = (float)hp[(size_t)s1 * 64];
            float a2 = (float)hp[(size_t)s2 * 64];
            float a3 = (float)hp[(size_t)s3 * 64];
            acc += (a0 + a1) + (a2 + a3);
        }
        for (; e < n; ++e) {
            int s0 = __shfl(idx, e);
            acc += (float)hp[(size_t)s0 * 64];
        }
    }
    acc = acc * dv + bias[lane];
    o[(size_t)node * 64 + lane] = acc;
}

// ---------------- launcher ----------------

extern "C" void kernel_launch(void* const* d_in, const int* in_sizes, int n_in,
                              void* d_out, int out_size, void* d_ws, size_t ws_size,
                              hipStream_t stream) {
    const float* x  = (const float*)d_in[0];
    const int*   ei = (const int*)d_in[1];
    const float* W1 = (const float*)d_in[2];
    const float* b1 = (const float*)d_in[3];
    const float* W2 = (const float*)d_in[4];
    const float* b2 = (const float*)d_in[5];
    float* out = (float*)d_out;

    const int N = in_sizes[0] / 128;
    const int E = in_sizes[1] / 2;
    const int* esrc = ei;
    const int* edst = ei + E;

    const int NB  = (N + 255) / 256;          // buckets (<=256 requires N<=65536)
    const int Gg1 = (N + 127) / 128;
    const int GA  = (E + 4095) / 4096;

    // workspace layout
    int* bucket_cnt = (int*)d_ws;                             // 256
    unsigned int* ebuf = (unsigned int*)(bucket_cnt + 256);   // NB*BKT_CAP packed edges
    unsigned short* ssrc = (unsigned short*)(ebuf + (size_t)NB * BKT_CAP); // E uint16
    int* rs = (int*)(ssrc + ((E + 1) & ~1));                  // N
    float* dinv = (float*)(rs + N);                           // N
    half_t* hs1 = (half_t*)(dinv + N);                        // N*128 fp16 (reused as hs2)
    half_t* g1  = hs1 + (size_t)N * 128;                      // N*128 fp16
    half_t* hs2 = hs1;

    hipMemsetAsync(bucket_cnt, 0, 256 * 4, stream);

    // k1: gemm1 (128x128 tiles, unscaled fp16 h1) ∪ pass-A edge binning
    hipLaunchKernelGGL(gemm_binA_k, dim3(Gg1 + GA), dim3(256), 0, stream,
                       x, W1, hs1, N, Gg1, esrc, edst, bucket_cnt, ebuf, E);
    // k2: per-bucket counting sort -> rs, dinv, ssrc
    hipLaunchKernelGGL(binB_k, dim3(NB), dim3(256), 0, stream,
                       bucket_cnt, ebuf, ssrc, rs, dinv, N, NB);
    // layer 1 aggregate
    hipLaunchKernelGGL(gather1_k, dim3((N + 3) / 4), dim3(256), 0, stream,
                       hs1, ssrc, rs, dinv, b1, g1, N, E);
    // layer 2
    hipLaunchKernelGGL(gemm2_k, dim3((N + 63) / 64), dim3(256), 0, stream,
                       g1, W2, dinv, hs2, N);
    hipLaunchKernelGGL(gather2_k, dim3((N + 3) / 4), dim3(256), 0, stream,
                       hs2, ssrc, rs, dinv, b2, out, N, E);
}

// Round 13
// 181.696 us; speedup vs baseline: 1.4882x; 1.0889x over previous
//
#include <hip/hip_runtime.h>
#include <hip/hip_fp16.h>

// GCN 2-layer, pull-based CSR gather, fp16 dense intermediates.
// R13: both GEMMs moved to f16 MFMA (mfma_f32_16x16x32_f16, fp32 accum).
// Inputs were already being rounded to fp16 at the hs/g1 boundary, so MFMA
// adds no meaningful error. gemm1: W1^T staged fp16 in LDS (pitch 136),
// A-frags direct from global w/ cvt (each x elem used once per block).
// Edge preprocessing (R12 bucket counting sort) unchanged.
// Assumes N <= 65536.

typedef _Float16 half_t;
typedef _Float16 half2_t __attribute__((ext_vector_type(2)));
typedef _Float16 f16x8 __attribute__((ext_vector_type(8)));
typedef float f32x4 __attribute__((ext_vector_type(4)));

#define BKT_CAP 8192   // per-bucket ebuf capacity (expected load 4096, sigma 64)

// inclusive block scan over 256 threads (4 waves); caller provides 4-int LDS
__device__ __forceinline__ int incl_scan256(int v, volatile int* wsum) {
    int t = threadIdx.x, lane = t & 63, w = t >> 6;
#pragma unroll
    for (int off = 1; off < 64; off <<= 1) {
        int u = __shfl_up(v, off);
        if (lane >= off) v += u;
    }
    if (lane == 63) wsum[w] = v;
    __syncthreads();
    int add = 0;
#pragma unroll
    for (int i = 0; i < 3; ++i)
        if (i < w) add += wsum[i];
    return v + add;
}

// ---------------- gemm1: 128x128 tile via f16 MFMA ----------------
// MFMA 16x16x32 layouts (gfx950, HW-verified mappings):
//   A-frag: lane holds A[m=lane&15][k = (lane>>4)*8 + j], j=0..7
//   B-frag: lane holds B[k = (lane>>4)*8 + j][n=lane&15]
//   C/D   : col = lane&15, row = (lane>>4)*4 + reg

__device__ __forceinline__ void gemm1_mfma(const float* __restrict__ x,
                                           const float* __restrict__ W,
                                           half_t* __restrict__ C, int M, int r0) {
    __shared__ _Float16 Wt[128][136];          // [n][k], pitch 136 (2-way-free)
    const int t = threadIdx.x;

    // stage W^T as fp16: i = k*128 + n over 16384 elems, float4 per thread-step
    for (int i = t * 4; i < 16384; i += 1024) {
        int k = i >> 7, n = i & 127;
        float4 w4 = *(const float4*)&W[i];
        Wt[n + 0][k] = (_Float16)w4.x;
        Wt[n + 1][k] = (_Float16)w4.y;
        Wt[n + 2][k] = (_Float16)w4.z;
        Wt[n + 3][k] = (_Float16)w4.w;
    }
    __syncthreads();

    const int w = t >> 6, lane = t & 63;
    const int m = lane & 15, q = lane >> 4;

    f32x4 acc[2][8];
#pragma unroll
    for (int rt = 0; rt < 2; ++rt)
#pragma unroll
        for (int ct = 0; ct < 8; ++ct)
#pragma unroll
            for (int r = 0; r < 4; ++r) acc[rt][ct][r] = 0.f;

#pragma unroll
    for (int kc = 0; kc < 4; ++kc) {
        const int k0 = kc * 32 + q * 8;
        f16x8 a[2];
#pragma unroll
        for (int rt = 0; rt < 2; ++rt) {
            int row = r0 + (w * 2 + rt) * 16 + m;
            if (row >= M) row = M - 1;
            const float* ap = &x[(size_t)row * 128 + k0];
            float4 lo = *(const float4*)ap;
            float4 hi = *(const float4*)(ap + 4);
            f16x8 av;
            av[0] = (_Float16)lo.x; av[1] = (_Float16)lo.y;
            av[2] = (_Float16)lo.z; av[3] = (_Float16)lo.w;
            av[4] = (_Float16)hi.x; av[5] = (_Float16)hi.y;
            av[6] = (_Float16)hi.z; av[7] = (_Float16)hi.w;
            a[rt] = av;
        }
#pragma unroll
        for (int ct = 0; ct < 8; ++ct) {
            f16x8 b = *(const f16x8*)&Wt[ct * 16 + m][k0];
            acc[0][ct] = __builtin_amdgcn_mfma_f32_16x16x32_f16(a[0], b, acc[0][ct], 0, 0, 0);
            acc[1][ct] = __builtin_amdgcn_mfma_f32_16x16x32_f16(a[1], b, acc[1][ct], 0, 0, 0);
        }
    }

#pragma unroll
    for (int rt = 0; rt < 2; ++rt)
#pragma unroll
        for (int ct = 0; ct < 8; ++ct)
#pragma unroll
            for (int r = 0; r < 4; ++r) {
                int row = r0 + (w * 2 + rt) * 16 + q * 4 + r;
                if (row < M)
                    C[(size_t)row * 128 + ct * 16 + m] = (half_t)acc[rt][ct][r];
            }
}

// ---------------- k1: gemm1 blocks, then pass-A binning blocks --------------

__launch_bounds__(256)
__global__ void gemm_binA_k(const float* __restrict__ A, const float* __restrict__ W,
                            half_t* __restrict__ C, int M, int Gg1,
                            const int* __restrict__ esrc, const int* __restrict__ edst,
                            int* __restrict__ bucket_cnt, unsigned int* __restrict__ ebuf,
                            int E) {
    int b = blockIdx.x;
    if (b < Gg1) {
        gemm1_mfma(A, W, C, M, b * 128);
        return;
    }
    __shared__ int cntA[256];
    __shared__ int curA[256];
    __shared__ int deltaA[256];
    __shared__ int wsumA[4];

    const int t = threadIdx.x;
    const int base = (b - Gg1) * 4096;
    int ls[16], ld[16];

    cntA[t] = 0;
    __syncthreads();
#pragma unroll
    for (int j = 0; j < 16; ++j) {
        int idx = base + j * 256 + t;
        if (idx < E) {
            ls[j] = esrc[idx];
            ld[j] = edst[idx];
            atomicAdd(&cntA[ld[j] >> 8], 1);
        } else {
            ls[j] = -1;
            ld[j] = 0;
        }
    }
    __syncthreads();

    int c = cntA[t];
    int incl = incl_scan256(c, wsumA);      // contains a __syncthreads
    int excl = incl - c;
    int gbase = atomicAdd(&bucket_cnt[t], c);       // offset within bucket segment
    deltaA[t] = t * BKT_CAP + gbase - excl;         // absolute = seg base + offset
    curA[t] = excl;
    __syncthreads();

#pragma unroll
    for (int j = 0; j < 16; ++j) {
        if (ls[j] >= 0) {
            int bkt = ld[j] >> 8;
            int p = atomicAdd(&curA[bkt], 1);
            ebuf[deltaA[bkt] + p] = ((unsigned int)ls[j] << 8) | ((unsigned int)ld[j] & 255u);
        }
    }
}

// ---------------- k2 (pass B): per-bucket counting sort -> rs/dinv/ssrc -----

__launch_bounds__(256)
__global__ void binB_k(const int* __restrict__ bucket_cnt,
                       const unsigned int* __restrict__ ebuf,
                       unsigned short* __restrict__ ssrc,
                       int* __restrict__ rs, float* __restrict__ dinv,
                       int N, int NB) {
    __shared__ int cnt[256];
    __shared__ int pre[256];
    __shared__ int wsum1[4];
    __shared__ int wsum2[4];

    const int t = threadIdx.x;
    const int b = blockIdx.x;

    int v = (t < NB) ? bucket_cnt[t] : 0;
    int inclb = incl_scan256(v, wsum1);
    pre[t] = inclb;
    __syncthreads();
    const int gb = (b > 0) ? pre[b - 1] : 0;
    const int sz = pre[b] - gb;
    const unsigned int* seg = ebuf + (size_t)b * BKT_CAP;

    cnt[t] = 0;
    __syncthreads();
    for (int i = t; i < sz; i += 256) {
        unsigned int pk = seg[i];
        atomicAdd(&cnt[pk & 255u], 1);
    }
    __syncthreads();

    int c = cnt[t];
    int incl = incl_scan256(c, wsum2);
    int excl = incl - c;
    int node = b * 256 + t;
    if (node < N) {
        rs[node] = gb + excl;
        dinv[node] = rsqrtf(1.0f + (float)c);
    }
    __syncthreads();
    cnt[t] = excl;
    __syncthreads();

    for (int i = t; i < sz; i += 256) {
        unsigned int pk = seg[i];
        int p = atomicAdd(&cnt[pk & 255u], 1);
        ssrc[gb + p] = (unsigned short)(pk >> 8);
    }
}

// ---------------- gather1: 128-dim, fold dinv[src] per edge, fp16 out+relu --
// out = relu( dv * ( h[node]*dv + sum_s h[s]*dinv[s] ) + b )

__global__ void gather1_k(const half_t* __restrict__ hs,
                          const unsigned short* __restrict__ ssrc,
                          const int* __restrict__ rs,
                          const float* __restrict__ dinv,
                          const float* __restrict__ bias,
                          half_t* __restrict__ o, int N, int E) {
    int node = (int)((blockIdx.x * blockDim.x + threadIdx.x) >> 6);
    int lane = threadIdx.x & 63;
    if (node >= N) return;

    int start = rs[node];
    int end = (node + 1 < N) ? rs[node + 1] : E;
    float dv = dinv[node];

    const half_t* hp = hs + 2 * lane;
    half2_t sv = *(const half2_t*)&hp[(size_t)node * 128];   // self loop
    float2 acc;
    acc.x = (float)sv.x * dv;        // epilogue multiplies by dv again -> dv^2
    acc.y = (float)sv.y * dv;
    for (int base = start; base < end; base += 64) {
        int n = end - base;
        if (n > 64) n = 64;
        int gi = (base + lane < end) ? (base + lane) : base;
        int idx = (int)ssrc[gi];
        float dw = dinv[idx];
        int e = 0;
        for (; e + 4 <= n; e += 4) {
            int s0 = __shfl(idx, e + 0);
            int s1 = __shfl(idx, e + 1);
            int s2 = __shfl(idx, e + 2);
            int s3 = __shfl(idx, e + 3);
            float w0 = __shfl(dw, e + 0);
            float w1 = __shfl(dw, e + 1);
            float w2 = __shfl(dw, e + 2);
            float w3 = __shfl(dw, e + 3);
            half2_t a0 = *(const half2_t*)&hp[(size_t)s0 * 128];
            half2_t a1 = *(const half2_t*)&hp[(size_t)s1 * 128];
            half2_t a2 = *(const half2_t*)&hp[(size_t)s2 * 128];
            half2_t a3 = *(const half2_t*)&hp[(size_t)s3 * 128];
            acc.x = fmaf((float)a0.x, w0, acc.x);
            acc.y = fmaf((float)a0.y, w0, acc.y);
            acc.x = fmaf((float)a1.x, w1, acc.x);
            acc.y = fmaf((float)a1.y, w1, acc.y);
            acc.x = fmaf((float)a2.x, w2, acc.x);
            acc.y = fmaf((float)a2.y, w2, acc.y);
            acc.x = fmaf((float)a3.x, w3, acc.x);
            acc.y = fmaf((float)a3.y, w3, acc.y);
        }
        for (; e < n; ++e) {
            int s0 = __shfl(idx, e);
            float w0 = __shfl(dw, e);
            half2_t a0 = *(const half2_t*)&hp[(size_t)s0 * 128];
            acc.x = fmaf((float)a0.x, w0, acc.x);
            acc.y = fmaf((float)a0.y, w0, acc.y);
        }
    }
    float2 bb = *(const float2*)&bias[2 * lane];
    acc.x = fmaxf(acc.x * dv + bb.x, 0.f);
    acc.y = fmaxf(acc.y * dv + bb.y, 0.f);
    half2_t st;
    st.x = (half_t)acc.x;
    st.y = (half_t)acc.y;
    *(half2_t*)&o[(size_t)node * 128 + 2 * lane] = st;
}

// ---------------- gemm2: [M,128]fp16 @ [128,64] -> fp16, *dinv[row], MFMA ---

__launch_bounds__(256)
__global__ void gemm2_k(const half_t* __restrict__ A, const float* __restrict__ W,
                        const float* __restrict__ dinv, half_t* __restrict__ C, int M) {
    __shared__ _Float16 Wt[64][136];           // [n][k]
    const int t = threadIdx.x;
    const int r0 = blockIdx.x * 128;

    // stage W2^T fp16: i = k*64 + n over 8192 elems
    for (int i = t * 4; i < 8192; i += 1024) {
        int k = i >> 6, n = i & 63;
        float4 w4 = *(const float4*)&W[i];
        Wt[n + 0][k] = (_Float16)w4.x;
        Wt[n + 1][k] = (_Float16)w4.y;
        Wt[n + 2][k] = (_Float16)w4.z;
        Wt[n + 3][k] = (_Float16)w4.w;
    }
    __syncthreads();

    const int w = t >> 6, lane = t & 63;
    const int m = lane & 15, q = lane >> 4;

    f32x4 acc[2][4];
#pragma unroll
    for (int rt = 0; rt < 2; ++rt)
#pragma unroll
        for (int ct = 0; ct < 4; ++ct)
#pragma unroll
            for (int r = 0; r < 4; ++r) acc[rt][ct][r] = 0.f;

#pragma unroll
    for (int kc = 0; kc < 4; ++kc) {
        const int k0 = kc * 32 + q * 8;
        f16x8 a[2];
#pragma unroll
        for (int rt = 0; rt < 2; ++rt) {
            int row = r0 + (w * 2 + rt) * 16 + m;
            if (row >= M) row = M - 1;
            a[rt] = *(const f16x8*)&A[(size_t)row * 128 + k0];
        }
#pragma unroll
        for (int ct = 0; ct < 4; ++ct) {
            f16x8 b = *(const f16x8*)&Wt[ct * 16 + m][k0];
            acc[0][ct] = __builtin_amdgcn_mfma_f32_16x16x32_f16(a[0], b, acc[0][ct], 0, 0, 0);
            acc[1][ct] = __builtin_amdgcn_mfma_f32_16x16x32_f16(a[1], b, acc[1][ct], 0, 0, 0);
        }
    }

#pragma unroll
    for (int rt = 0; rt < 2; ++rt)
#pragma unroll
        for (int ct = 0; ct < 4; ++ct)
#pragma unroll
            for (int r = 0; r < 4; ++r) {
                int row = r0 + (w * 2 + rt) * 16 + q * 4 + r;
                if (row < M) {
                    float s = dinv[row];
                    C[(size_t)row * 64 + ct * 16 + m] = (half_t)(acc[rt][ct][r] * s);
                }
            }
}

// ---------------- gather2: 64-dim, hs pre-scaled, fp32 out ------------------

__global__ void gather2_k(const half_t* __restrict__ hs,
                          const unsigned short* __restrict__ ssrc,
                          const int* __restrict__ rs,
                          const float* __restrict__ dinv,
                          const float* __restrict__ bias,
                          float* __restrict__ o, int N, int E) {
    int node = (int)((blockIdx.x * blockDim.x + threadIdx.x) >> 6);
    int lane = threadIdx.x & 63;
    if (node >= N) return;

    int start = rs[node];
    int end = (node + 1 < N) ? rs[node + 1] : E;
    float dv = dinv[node];

    const half_t* hp = hs + lane;
    float acc = (float)hp[(size_t)node * 64];
    for (int base = start; base < end; base += 64) {
        int n = end - base;
        if (n > 64) n = 64;
        int gi = (base + lane < end) ? (base + lane) : base;
        int idx = (int)ssrc[gi];
        int e = 0;
        for (; e + 4 <= n; e += 4) {
            int s0 = __shfl(idx, e + 0);
            int s1 = __shfl(idx, e + 1);
            int s2 = __shfl(idx, e + 2);
            int s3 = __shfl(idx, e + 3);
            float a0 = (float)hp[(size_t)s0 * 64];
            float a1 = (float)hp[(size_t)s1 * 64];
            float a2 = (float)hp[(size_t)s2 * 64];
            float a3 = (float)hp[(size_t)s3 * 64];
            acc += (a0 + a1) + (a2 + a3);
        }
        for (; e < n; ++e) {
            int s0 = __shfl(idx, e);
            acc += (float)hp[(size_t)s0 * 64];
        }
    }
    acc = acc * dv + bias[lane];
    o[(size_t)node * 64 + lane] = acc;
}

// ---------------- launcher ----------------

extern "C" void kernel_launch(void* const* d_in, const int* in_sizes, int n_in,
                              void* d_out, int out_size, void* d_ws, size_t ws_size,
                              hipStream_t stream) {
    const float* x  = (const float*)d_in[0];
    const int*   ei = (const int*)d_in[1];
    const float* W1 = (const float*)d_in[2];
    const float* b1 = (const float*)d_in[3];
    const float* W2 = (const float*)d_in[4];
    const float* b2 = (const float*)d_in[5];
    float* out = (float*)d_out;

    const int N = in_sizes[0] / 128;
    const int E = in_sizes[1] / 2;
    const int* esrc = ei;
    const int* edst = ei + E;

    const int NB  = (N + 255) / 256;          // buckets (<=256 requires N<=65536)
    const int Gg1 = (N + 127) / 128;
    const int GA  = (E + 4095) / 4096;

    // workspace layout
    int* bucket_cnt = (int*)d_ws;                             // 256
    unsigned int* ebuf = (unsigned int*)(bucket_cnt + 256);   // NB*BKT_CAP packed edges
    unsigned short* ssrc = (unsigned short*)(ebuf + (size_t)NB * BKT_CAP); // E uint16
    int* rs = (int*)(ssrc + ((E + 1) & ~1));                  // N
    float* dinv = (float*)(rs + N);                           // N
    half_t* hs1 = (half_t*)(dinv + N);                        // N*128 fp16 (reused as hs2)
    half_t* g1  = hs1 + (size_t)N * 128;                      // N*128 fp16
    half_t* hs2 = hs1;

    hipMemsetAsync(bucket_cnt, 0, 256 * 4, stream);

    // k1: gemm1 (128x128 MFMA tiles, unscaled fp16 h1) ∪ pass-A edge binning
    hipLaunchKernelGGL(gemm_binA_k, dim3(Gg1 + GA), dim3(256), 0, stream,
                       x, W1, hs1, N, Gg1, esrc, edst, bucket_cnt, ebuf, E);
    // k2: per-bucket counting sort -> rs, dinv, ssrc
    hipLaunchKernelGGL(binB_k, dim3(NB), dim3(256), 0, stream,
                       bucket_cnt, ebuf, ssrc, rs, dinv, N, NB);
    // layer 1 aggregate
    hipLaunchKernelGGL(gather1_k, dim3((N + 3) / 4), dim3(256), 0, stream,
                       hs1, ssrc, rs, dinv, b1, g1, N, E);
    // layer 2
    hipLaunchKernelGGL(gemm2_k, dim3((N + 127) / 128), dim3(256), 0, stream,
                       g1, W2, dinv, hs2, N);
    hipLaunchKernelGGL(gather2_k, dim3((N + 3) / 4), dim3(256), 0, stream,
                       hs2, ssrc, rs, dinv, b2, out, N, E);
}

// Round 14
// 179.713 us; speedup vs baseline: 1.5046x; 1.0110x over previous
//
#include <hip/hip_runtime.h>
#include <hip/hip_fp16.h>

// GCN 2-layer, pull-based CSR gather, fp16 dense intermediates.
// R14 = R13 + gemm staging fixes: (a) Wt^T staged with coalesced global
// reads along n + b64 LDS writes along k (was: 16-way-conflicting scalar
// writes, 3.4M SQ_LDS_BANK_CONFLICT); (b) gemm1 A-fragments staged through
// LDS (Xs chunk, coalesced float4 reads) instead of per-lane 32B global
// loads from 16 different rows per wave-inst.
// Edge preprocessing (R12 bucket counting sort) unchanged. N <= 65536.

typedef _Float16 half_t;
typedef _Float16 half2_t __attribute__((ext_vector_type(2)));
typedef _Float16 f16x4 __attribute__((ext_vector_type(4)));
typedef _Float16 f16x8 __attribute__((ext_vector_type(8)));
typedef float f32x4 __attribute__((ext_vector_type(4)));

#define BKT_CAP 8192   // per-bucket ebuf capacity (expected load 4096, sigma 64)

// inclusive block scan over 256 threads (4 waves); caller provides 4-int LDS
__device__ __forceinline__ int incl_scan256(int v, volatile int* wsum) {
    int t = threadIdx.x, lane = t & 63, w = t >> 6;
#pragma unroll
    for (int off = 1; off < 64; off <<= 1) {
        int u = __shfl_up(v, off);
        if (lane >= off) v += u;
    }
    if (lane == 63) wsum[w] = v;
    __syncthreads();
    int add = 0;
#pragma unroll
    for (int i = 0; i < 3; ++i)
        if (i < w) add += wsum[i];
    return v + add;
}

// ---------------- gemm1: 128x128 tile via f16 MFMA ----------------
// MFMA 16x16x32 layouts (gfx950, HW-verified):
//   A-frag: lane holds A[m=lane&15][k=(lane>>4)*8+j]
//   B-frag: lane holds B[k=(lane>>4)*8+j][n=lane&15]
//   C/D   : col=lane&15, row=(lane>>4)*4+reg

__device__ __forceinline__ void gemm1_mfma(const float* __restrict__ x,
                                           const float* __restrict__ W,
                                           half_t* __restrict__ C, int M, int r0) {
    __shared__ _Float16 Wt[128][136];          // [n][k], rows 272B (b128-aligned)
    __shared__ _Float16 Xs[128][40];           // [m][k-chunk], rows 80B
    const int t = threadIdx.x;

    // stage W^T fp16: coalesced reads along n, b64 writes along k
    {
        const int n = t & 127;
#pragma unroll
        for (int kb = (t >> 7) * 4; kb < 128; kb += 8) {
            f16x4 hv;
            hv[0] = (_Float16)W[(size_t)(kb + 0) * 128 + n];
            hv[1] = (_Float16)W[(size_t)(kb + 1) * 128 + n];
            hv[2] = (_Float16)W[(size_t)(kb + 2) * 128 + n];
            hv[3] = (_Float16)W[(size_t)(kb + 3) * 128 + n];
            *(f16x4*)&Wt[n][kb] = hv;
        }
    }

    const int w = t >> 6, lane = t & 63;
    const int m = lane & 15, q = lane >> 4;

    // Xs staging coords: 16 floats (one row-half-chunk) per thread per kc
    const int sr = t >> 1;               // 0..127 tile row
    const int sk = (t & 1) * 16;         // 0 or 16 within 32-k chunk
    const int srow = (r0 + sr < M) ? (r0 + sr) : (M - 1);

    f32x4 acc[2][8];
#pragma unroll
    for (int rt = 0; rt < 2; ++rt)
#pragma unroll
        for (int ct = 0; ct < 8; ++ct)
#pragma unroll
            for (int r = 0; r < 4; ++r) acc[rt][ct][r] = 0.f;

#pragma unroll
    for (int kc = 0; kc < 4; ++kc) {
        // coalesced global loads issued before the barrier (overlap prev MFMAs)
        const float* xp = &x[(size_t)srow * 128 + kc * 32 + sk];
        float4 v0 = *(const float4*)xp;
        float4 v1 = *(const float4*)(xp + 4);
        float4 v2 = *(const float4*)(xp + 8);
        float4 v3 = *(const float4*)(xp + 12);
        __syncthreads();                 // prev iter's Xs reads done (&& Wt staged)
        f16x8 s0, s1;
        s0[0] = (_Float16)v0.x; s0[1] = (_Float16)v0.y;
        s0[2] = (_Float16)v0.z; s0[3] = (_Float16)v0.w;
        s0[4] = (_Float16)v1.x; s0[5] = (_Float16)v1.y;
        s0[6] = (_Float16)v1.z; s0[7] = (_Float16)v1.w;
        s1[0] = (_Float16)v2.x; s1[1] = (_Float16)v2.y;
        s1[2] = (_Float16)v2.z; s1[3] = (_Float16)v2.w;
        s1[4] = (_Float16)v3.x; s1[5] = (_Float16)v3.y;
        s1[6] = (_Float16)v3.z; s1[7] = (_Float16)v3.w;
        *(f16x8*)&Xs[sr][sk] = s0;
        *(f16x8*)&Xs[sr][sk + 8] = s1;
        __syncthreads();

        const int k0 = q * 8;
        f16x8 a0 = *(const f16x8*)&Xs[(w * 2 + 0) * 16 + m][k0];
        f16x8 a1 = *(const f16x8*)&Xs[(w * 2 + 1) * 16 + m][k0];
        const int kw = kc * 32 + k0;
#pragma unroll
        for (int ct = 0; ct < 8; ++ct) {
            f16x8 b = *(const f16x8*)&Wt[ct * 16 + m][kw];
            acc[0][ct] = __builtin_amdgcn_mfma_f32_16x16x32_f16(a0, b, acc[0][ct], 0, 0, 0);
            acc[1][ct] = __builtin_amdgcn_mfma_f32_16x16x32_f16(a1, b, acc[1][ct], 0, 0, 0);
        }
    }

#pragma unroll
    for (int rt = 0; rt < 2; ++rt)
#pragma unroll
        for (int ct = 0; ct < 8; ++ct)
#pragma unroll
            for (int r = 0; r < 4; ++r) {
                int row = r0 + (w * 2 + rt) * 16 + q * 4 + r;
                if (row < M)
                    C[(size_t)row * 128 + ct * 16 + m] = (half_t)acc[rt][ct][r];
            }
}

// ---------------- k1: gemm1 blocks, then pass-A binning blocks --------------

__launch_bounds__(256)
__global__ void gemm_binA_k(const float* __restrict__ A, const float* __restrict__ W,
                            half_t* __restrict__ C, int M, int Gg1,
                            const int* __restrict__ esrc, const int* __restrict__ edst,
                            int* __restrict__ bucket_cnt, unsigned int* __restrict__ ebuf,
                            int E) {
    int b = blockIdx.x;
    if (b < Gg1) {
        gemm1_mfma(A, W, C, M, b * 128);
        return;
    }
    __shared__ int cntA[256];
    __shared__ int curA[256];
    __shared__ int deltaA[256];
    __shared__ int wsumA[4];

    const int t = threadIdx.x;
    const int base = (b - Gg1) * 4096;
    int ls[16], ld[16];

    cntA[t] = 0;
    __syncthreads();
#pragma unroll
    for (int j = 0; j < 16; ++j) {
        int idx = base + j * 256 + t;
        if (idx < E) {
            ls[j] = esrc[idx];
            ld[j] = edst[idx];
            atomicAdd(&cntA[ld[j] >> 8], 1);
        } else {
            ls[j] = -1;
            ld[j] = 0;
        }
    }
    __syncthreads();

    int c = cntA[t];
    int incl = incl_scan256(c, wsumA);      // contains a __syncthreads
    int excl = incl - c;
    int gbase = atomicAdd(&bucket_cnt[t], c);       // offset within bucket segment
    deltaA[t] = t * BKT_CAP + gbase - excl;         // absolute = seg base + offset
    curA[t] = excl;
    __syncthreads();

#pragma unroll
    for (int j = 0; j < 16; ++j) {
        if (ls[j] >= 0) {
            int bkt = ld[j] >> 8;
            int p = atomicAdd(&curA[bkt], 1);
            ebuf[deltaA[bkt] + p] = ((unsigned int)ls[j] << 8) | ((unsigned int)ld[j] & 255u);
        }
    }
}

// ---------------- k2 (pass B): per-bucket counting sort -> rs/dinv/ssrc -----

__launch_bounds__(256)
__global__ void binB_k(const int* __restrict__ bucket_cnt,
                       const unsigned int* __restrict__ ebuf,
                       unsigned short* __restrict__ ssrc,
                       int* __restrict__ rs, float* __restrict__ dinv,
                       int N, int NB) {
    __shared__ int cnt[256];
    __shared__ int pre[256];
    __shared__ int wsum1[4];
    __shared__ int wsum2[4];

    const int t = threadIdx.x;
    const int b = blockIdx.x;

    int v = (t < NB) ? bucket_cnt[t] : 0;
    int inclb = incl_scan256(v, wsum1);
    pre[t] = inclb;
    __syncthreads();
    const int gb = (b > 0) ? pre[b - 1] : 0;
    const int sz = pre[b] - gb;
    const unsigned int* seg = ebuf + (size_t)b * BKT_CAP;

    cnt[t] = 0;
    __syncthreads();
    for (int i = t; i < sz; i += 256) {
        unsigned int pk = seg[i];
        atomicAdd(&cnt[pk & 255u], 1);
    }
    __syncthreads();

    int c = cnt[t];
    int incl = incl_scan256(c, wsum2);
    int excl = incl - c;
    int node = b * 256 + t;
    if (node < N) {
        rs[node] = gb + excl;
        dinv[node] = rsqrtf(1.0f + (float)c);
    }
    __syncthreads();
    cnt[t] = excl;
    __syncthreads();

    for (int i = t; i < sz; i += 256) {
        unsigned int pk = seg[i];
        int p = atomicAdd(&cnt[pk & 255u], 1);
        ssrc[gb + p] = (unsigned short)(pk >> 8);
    }
}

// ---------------- gather1: 128-dim, fold dinv[src] per edge, fp16 out+relu --
// out = relu( dv * ( h[node]*dv + sum_s h[s]*dinv[s] ) + b )

__global__ void gather1_k(const half_t* __restrict__ hs,
                          const unsigned short* __restrict__ ssrc,
                          const int* __restrict__ rs,
                          const float* __restrict__ dinv,
                          const float* __restrict__ bias,
                          half_t* __restrict__ o, int N, int E) {
    int node = (int)((blockIdx.x * blockDim.x + threadIdx.x) >> 6);
    int lane = threadIdx.x & 63;
    if (node >= N) return;

    int start = rs[node];
    int end = (node + 1 < N) ? rs[node + 1] : E;
    float dv = dinv[node];

    const half_t* hp = hs + 2 * lane;
    half2_t sv = *(const half2_t*)&hp[(size_t)node * 128];   // self loop
    float2 acc;
    acc.x = (float)sv.x * dv;        // epilogue multiplies by dv again -> dv^2
    acc.y = (float)sv.y * dv;
    for (int base = start; base < end; base += 64) {
        int n = end - base;
        if (n > 64) n = 64;
        int gi = (base + lane < end) ? (base + lane) : base;
        int idx = (int)ssrc[gi];
        float dw = dinv[idx];
        int e = 0;
        for (; e + 4 <= n; e += 4) {
            int s0 = __shfl(idx, e + 0);
            int s1 = __shfl(idx, e + 1);
            int s2 = __shfl(idx, e + 2);
            int s3 = __shfl(idx, e + 3);
            float w0 = __shfl(dw, e + 0);
            float w1 = __shfl(dw, e + 1);
            float w2 = __shfl(dw, e + 2);
            float w3 = __shfl(dw, e + 3);
            half2_t a0 = *(const half2_t*)&hp[(size_t)s0 * 128];
            half2_t a1 = *(const half2_t*)&hp[(size_t)s1 * 128];
            half2_t a2 = *(const half2_t*)&hp[(size_t)s2 * 128];
            half2_t a3 = *(const half2_t*)&hp[(size_t)s3 * 128];
            acc.x = fmaf((float)a0.x, w0, acc.x);
            acc.y = fmaf((float)a0.y, w0, acc.y);
            acc.x = fmaf((float)a1.x, w1, acc.x);
            acc.y = fmaf((float)a1.y, w1, acc.y);
            acc.x = fmaf((float)a2.x, w2, acc.x);
            acc.y = fmaf((float)a2.y, w2, acc.y);
            acc.x = fmaf((float)a3.x, w3, acc.x);
            acc.y = fmaf((float)a3.y, w3, acc.y);
        }
        for (; e < n; ++e) {
            int s0 = __shfl(idx, e);
            float w0 = __shfl(dw, e);
            half2_t a0 = *(const half2_t*)&hp[(size_t)s0 * 128];
            acc.x = fmaf((float)a0.x, w0, acc.x);
            acc.y = fmaf((float)a0.y, w0, acc.y);
        }
    }
    float2 bb = *(const float2*)&bias[2 * lane];
    acc.x = fmaxf(acc.x * dv + bb.x, 0.f);
    acc.y = fmaxf(acc.y * dv + bb.y, 0.f);
    half2_t st;
    st.x = (half_t)acc.x;
    st.y = (half_t)acc.y;
    *(half2_t*)&o[(size_t)node * 128 + 2 * lane] = st;
}

// ---------------- gemm2: [M,128]fp16 @ [128,64] -> fp16, *dinv[row], MFMA ---

__launch_bounds__(256)
__global__ void gemm2_k(const half_t* __restrict__ A, const float* __restrict__ W,
                        const float* __restrict__ dinv, half_t* __restrict__ C, int M) {
    __shared__ _Float16 Wt[64][136];           // [n][k]
    const int t = threadIdx.x;
    const int r0 = blockIdx.x * 128;

    // stage W2^T fp16: coalesced reads along n, b64 writes along k
    {
        const int n = t & 63;
#pragma unroll
        for (int kb = (t >> 6) * 4; kb < 128; kb += 16) {
            f16x4 hv;
            hv[0] = (_Float16)W[(size_t)(kb + 0) * 64 + n];
            hv[1] = (_Float16)W[(size_t)(kb + 1) * 64 + n];
            hv[2] = (_Float16)W[(size_t)(kb + 2) * 64 + n];
            hv[3] = (_Float16)W[(size_t)(kb + 3) * 64 + n];
            *(f16x4*)&Wt[n][kb] = hv;
        }
    }
    __syncthreads();

    const int w = t >> 6, lane = t & 63;
    const int m = lane & 15, q = lane >> 4;

    f32x4 acc[2][4];
#pragma unroll
    for (int rt = 0; rt < 2; ++rt)
#pragma unroll
        for (int ct = 0; ct < 4; ++ct)
#pragma unroll
            for (int r = 0; r < 4; ++r) acc[rt][ct][r] = 0.f;

#pragma unroll
    for (int kc = 0; kc < 4; ++kc) {
        const int k0 = kc * 32 + q * 8;
        f16x8 a[2];
#pragma unroll
        for (int rt = 0; rt < 2; ++rt) {
            int row = r0 + (w * 2 + rt) * 16 + m;
            if (row >= M) row = M - 1;
            a[rt] = *(const f16x8*)&A[(size_t)row * 128 + k0];
        }
#pragma unroll
        for (int ct = 0; ct < 4; ++ct) {
            f16x8 b = *(const f16x8*)&Wt[ct * 16 + m][k0];
            acc[0][ct] = __builtin_amdgcn_mfma_f32_16x16x32_f16(a[0], b, acc[0][ct], 0, 0, 0);
            acc[1][ct] = __builtin_amdgcn_mfma_f32_16x16x32_f16(a[1], b, acc[1][ct], 0, 0, 0);
        }
    }

#pragma unroll
    for (int rt = 0; rt < 2; ++rt)
#pragma unroll
        for (int ct = 0; ct < 4; ++ct)
#pragma unroll
            for (int r = 0; r < 4; ++r) {
                int row = r0 + (w * 2 + rt) * 16 + q * 4 + r;
                if (row < M) {
                    float s = dinv[row];
                    C[(size_t)row * 64 + ct * 16 + m] = (half_t)(acc[rt][ct][r] * s);
                }
            }
}

// ---------------- gather2: 64-dim, hs pre-scaled, fp32 out ------------------

__global__ void gather2_k(const half_t* __restrict__ hs,
                          const unsigned short* __restrict__ ssrc,
                          const int* __restrict__ rs,
                          const float* __restrict__ dinv,
                          const float* __restrict__ bias,
                          float* __restrict__ o, int N, int E) {
    int node = (int)((blockIdx.x * blockDim.x + threadIdx.x) >> 6);
    int lane = threadIdx.x & 63;
    if (node >= N) return;

    int start = rs[node];
    int end = (node + 1 < N) ? rs[node + 1] : E;
    float dv = dinv[node];

    const half_t* hp = hs + lane;
    float acc = (float)hp[(size_t)node * 64];
    for (int base = start; base < end; base += 64) {
        int n = end - base;
        if (n > 64) n = 64;
        int gi = (base + lane < end) ? (base + lane) : base;
        int idx = (int)ssrc[gi];
        int e = 0;
        for (; e + 4 <= n; e += 4) {
            int s0 = __shfl(idx, e + 0);
            int s1 = __shfl(idx, e + 1);
            int s2 = __shfl(idx, e + 2);
            int s3 = __shfl(idx, e + 3);
            float a0 = (float)hp[(size_t)s0 * 64];
            float a1 = (float)hp[(size_t)s1 * 64];
            float a2 = (float)hp[(size_t)s2 * 64];
            float a3 = (float)hp[(size_t)s3 * 64];
            acc += (a0 + a1) + (a2 + a3);
        }
        for (; e < n; ++e) {
            int s0 = __shfl(idx, e);
            acc += (float)hp[(size_t)s0 * 64];
        }
    }
    acc = acc * dv + bias[lane];
    o[(size_t)node * 64 + lane] = acc;
}

// ---------------- launcher ----------------

extern "C" void kernel_launch(void* const* d_in, const int* in_sizes, int n_in,
                              void* d_out, int out_size, void* d_ws, size_t ws_size,
                              hipStream_t stream) {
    const float* x  = (const float*)d_in[0];
    const int*   ei = (const int*)d_in[1];
    const float* W1 = (const float*)d_in[2];
    const float* b1 = (const float*)d_in[3];
    const float* W2 = (const float*)d_in[4];
    const float* b2 = (const float*)d_in[5];
    float* out = (float*)d_out;

    const int N = in_sizes[0] / 128;
    const int E = in_sizes[1] / 2;
    const int* esrc = ei;
    const int* edst = ei + E;

    const int NB  = (N + 255) / 256;          // buckets (<=256 requires N<=65536)
    const int Gg1 = (N + 127) / 128;
    const int GA  = (E + 4095) / 4096;

    // workspace layout
    int* bucket_cnt = (int*)d_ws;                             // 256
    unsigned int* ebuf = (unsigned int*)(bucket_cnt + 256);   // NB*BKT_CAP packed edges
    unsigned short* ssrc = (unsigned short*)(ebuf + (size_t)NB * BKT_CAP); // E uint16
    int* rs = (int*)(ssrc + ((E + 1) & ~1));                  // N
    float* dinv = (float*)(rs + N);                           // N
    half_t* hs1 = (half_t*)(dinv + N);                        // N*128 fp16 (reused as hs2)
    half_t* g1  = hs1 + (size_t)N * 128;                      // N*128 fp16
    half_t* hs2 = hs1;

    hipMemsetAsync(bucket_cnt, 0, 256 * 4, stream);

    // k1: gemm1 (128x128 MFMA tiles, unscaled fp16 h1) ∪ pass-A edge binning
    hipLaunchKernelGGL(gemm_binA_k, dim3(Gg1 + GA), dim3(256), 0, stream,
                       x, W1, hs1, N, Gg1, esrc, edst, bucket_cnt, ebuf, E);
    // k2: per-bucket counting sort -> rs, dinv, ssrc
    hipLaunchKernelGGL(binB_k, dim3(NB), dim3(256), 0, stream,
                       bucket_cnt, ebuf, ssrc, rs, dinv, N, NB);
    // layer 1 aggregate
    hipLaunchKernelGGL(gather1_k, dim3((N + 3) / 4), dim3(256), 0, stream,
                       hs1, ssrc, rs, dinv, b1, g1, N, E);
    // layer 2
    hipLaunchKernelGGL(gemm2_k, dim3((N + 127) / 128), dim3(256), 0, stream,
                       g1, W2, dinv, hs2, N);
    hipLaunchKernelGGL(gather2_k, dim3((N + 3) / 4), dim3(256), 0, stream,
                       hs2, ssrc, rs, dinv, b2, out, N, E);
}